// Round 3
// baseline (187.862 us; speedup 1.0000x reference)
//
#include <hip/hip_runtime.h>
#include <hip/hip_bf16.h>
#include <math.h>

typedef unsigned int uint;
typedef unsigned short ushort;
typedef __attribute__((ext_vector_type(8))) short short8;
typedef __attribute__((ext_vector_type(4))) float f32x4;

#define K_DIM 8192
#define ROWB 16384  // K_DIM * 2 bytes per row of XT / YT
#define N_TILE 78   // 32 XY + 36 XX-tri + 10 YY-tri (256x256 tiles)
#define S_SPLIT 3

// ws layout (bytes):
//   0        : double sums[4]           (xy, xx, yy)
//   256      : float  csx[2048]
//   8448     : float  csy[1024]
//   16384    : ushort XT[2048][8192]    centered x^T, bf16, swizzled (32 MB)
//   33570816 : ushort YT[1024][8192]    centered y^T, bf16, swizzled (16 MB)
//   50348032 : float  C[78][65536]      partial-C accumulators (19.5 MB)
// total = 70795264 B. Fallback to no-split path if ws_size smaller.

__device__ __forceinline__ ushort f2bf(float f) {
  uint x = __float_as_uint(f);
  uint r = (x + 0x7fffu + ((x >> 16) & 1u)) >> 16;  // RTNE
  return (ushort)r;
}

__device__ __forceinline__ void async16(const void* g, void* l) {
  __builtin_amdgcn_global_load_lds(
      (const __attribute__((address_space(1))) unsigned int*)g,
      (__attribute__((address_space(3))) unsigned int*)l, 16, 0, 0);
}

__global__ __launch_bounds__(256) void zero_k(double* sums, float* csx, float* csy) {
  int t = threadIdx.x;
  if (t < 4) sums[t] = 0.0;
  for (int i = t; i < 2048; i += 256) csx[i] = 0.f;
  for (int i = t; i < 1024; i += 256) csy[i] = 0.f;
}

__global__ __launch_bounds__(256) void zeroC_k(float* C) {
  // 78*65536 floats = 5111808 ; 1248 blocks * 256 thr * 16 floats
  size_t base = ((size_t)blockIdx.x * 256 + threadIdx.x) * 16;
  float4 z = make_float4(0.f, 0.f, 0.f, 0.f);
#pragma unroll
  for (int j = 0; j < 4; j++) *(float4*)(C + base + j * 4) = z;
}

// 192 blocks: 0..127 -> x, 128..191 -> y
__global__ __launch_bounds__(256) void colsum_k(const float* __restrict__ x,
                                                const float* __restrict__ y,
                                                float* csx, float* csy) {
  int bid = blockIdx.x, t = threadIdx.x;
  const float* src; float* dst; int C, cb, rb;
  if (bid < 128) { src = x; dst = csx; C = 2048; cb = bid & 7; rb = bid >> 3; }
  else { int b = bid - 128; src = y; dst = csy; C = 1024; cb = b & 3; rb = b >> 2; }
  int col = cb * 256 + t;
  size_t base = (size_t)(rb * 512) * (size_t)C + (size_t)col;
  float s = 0.f;
  for (int r = 0; r < 512; r++) s += src[base + (size_t)r * C];
  atomicAdd(&dst[col], s);
}

// Center + transpose + bf16 + swizzle. 64x64 tiles.
__global__ __launch_bounds__(256) void centerT_k(const float* __restrict__ x,
                                                 const float* __restrict__ y,
                                                 const float* __restrict__ csx,
                                                 const float* __restrict__ csy,
                                                 ushort* XT, ushort* YT) {
  __shared__ float tile[64][65];
  int bid = blockIdx.x, t = threadIdx.x;
  const float* src; const float* cs; char* dst; int C, mt, kt;
  if (bid < 4096) { src = x; cs = csx; dst = (char*)XT; C = 2048; mt = bid >> 7; kt = bid & 127; }
  else { int b = bid - 4096; src = y; cs = csy; dst = (char*)YT; C = 1024; mt = b >> 7; kt = b & 127; }
  int m0 = mt * 64, k0 = kt * 64;

#pragma unroll
  for (int rep = 0; rep < 16; rep++) {
    int idx = rep * 256 + t;
    int kr = idx >> 6, mc = idx & 63;
    tile[kr][mc] = src[(size_t)(k0 + kr) * C + (size_t)(m0 + mc)];
  }
  __syncthreads();

  const float inv_n = 1.0f / 8192.0f;
#pragma unroll
  for (int rep = 0; rep < 2; rep++) {
    int uid = rep * 256 + t;
    int ml = uid >> 3, u = uid & 7;
    int m = m0 + ml;
    float mean = cs[m] * inv_n;
    uint wds[4];
#pragma unroll
    for (int j = 0; j < 4; j++) {
      float f0 = tile[u * 8 + 2 * j][ml] - mean;
      float f1 = tile[u * 8 + 2 * j + 1][ml] - mean;
      wds[j] = (uint)f2bf(f0) | ((uint)f2bf(f1) << 16);
    }
    size_t off = (size_t)m * ROWB + (size_t)(k0 >> 6) * 128 + (size_t)((u ^ (m & 7)) << 4);
    uint4 v; v.x = wds[0]; v.y = wds[1]; v.z = wds[2]; v.w = wds[3];
    *(uint4*)(dst + off) = v;
  }
}

// Tile decomposition shared by gemm_split_k / reduceC_k.
// tile in [0,78): <32 XY ; <68 XX-tri ; else YY-tri.
__device__ __forceinline__ void tile_decomp(int tile, int* m0, int* n0,
                                            int* which,  // 0=XY 1=XX 2=YY
                                            int* diag) {
  if (tile < 32) { *m0 = (tile >> 2) * 256; *n0 = (tile & 3) * 256; *which = 0; *diag = 0; }
  else if (tile < 68) {
    int idx = tile - 32, ti = 0;
    while (idx >= 8 - ti) { idx -= 8 - ti; ti++; }
    *m0 = ti * 256; *n0 = (ti + idx) * 256; *which = 1; *diag = (idx == 0);
  } else {
    int idx = tile - 68, ti = 0;
    while (idx >= 4 - ti) { idx -= 4 - ti; ti++; }
    *m0 = ti * 256; *n0 = (ti + idx) * 256; *which = 2; *diag = (idx == 0);
  }
}

// K-split GEMM: 78 tiles x 3 K-chunks = 234 blocks x 512 threads (8 waves).
// Tile 256x256, BK=64, double-buffered 128 KiB LDS, 2-phase pipeline.
// Wave grid 4(M) x 2(N): each wave owns 64 rows x 128 cols = 4x8 frags 16x16.
// Partial C accumulated into Cbuf[tile] via mapping-free bijection
// (wave,frag,e,lane) -> slot; identical across the 3 sibling chunks.
__global__ __launch_bounds__(512, 2) void gemm_split_k(const ushort* __restrict__ XT,
                                                       const ushort* __restrict__ YT,
                                                       float* __restrict__ Cbuf) {
  __shared__ char lds[131072];  // 2 bufs x (A 32K + B 32K)

  int bid = blockIdx.x;
  int tile = bid / S_SPLIT, s = bid - tile * S_SPLIT;
  int m0, n0, which, diag;
  tile_decomp(tile, &m0, &n0, &which, &diag);
  const char* Ab = (const char*)((which == 2) ? YT : XT);
  const char* Bb = (const char*)((which == 0) ? YT : (which == 1) ? (const ushort*)XT : YT);

  int k0 = (128 * s) / S_SPLIT;        // 0,42,85
  int k1 = (128 * (s + 1)) / S_SPLIT;  // 42,85,128
  int nst = k1 - k0;

  int t = threadIdx.x;
  int u = t & 7;          // 16B unit within a row's 128B chunk
  int r8 = t >> 3;        // 0..63 staging row group
  int w = t >> 6;         // wave 0..7
  int lane = t & 63;
  int wr = w >> 1, wc = w & 1;        // 4x2 wave grid
  int lr = lane & 15, lk = lane >> 4; // frag row / k-unit

  f32x4 acc[4][8];
#pragma unroll
  for (int i = 0; i < 4; i++)
#pragma unroll
    for (int j = 0; j < 8; j++)
      acc[i][j] = (f32x4){0.f, 0.f, 0.f, 0.f};

  const size_t abase = (size_t)m0 * ROWB + (size_t)(u * 16);
  const size_t bbase = (size_t)n0 * ROWB + (size_t)(u * 16);

#define STAGE(buf, step)                                                          \
  {                                                                               \
    size_t koff = (size_t)(step) * 128;                                           \
    char* la_ = lds + (buf) * 65536;                                              \
    char* lb_ = la_ + 32768;                                                      \
    _Pragma("unroll")                                                             \
    for (int c = 0; c < 4; c++) {                                                 \
      int row = c * 64 + r8;                                                      \
      async16(Ab + abase + (size_t)row * ROWB + koff, la_ + row * 128 + u * 16);  \
      async16(Bb + bbase + (size_t)row * ROWB + koff, lb_ + row * 128 + u * 16);  \
    }                                                                             \
  }

  STAGE(0, k0);
  __syncthreads();  // drains vmcnt(0): buf0 ready

  for (int i = 0; i < nst; ++i) {
    int cur = i & 1;
    if (i + 1 < nst) STAGE(cur ^ 1, k0 + i + 1);  // issue next-tile loads FIRST

    const char* la = lds + cur * 65536;
    const char* lb = la + 32768;
#pragma unroll
    for (int ks = 0; ks < 2; ks++) {
      int ku = ks * 4 + lk;
      short8 a[4], b[8];
#pragma unroll
      for (int mi = 0; mi < 4; mi++) {
        int row = wr * 64 + mi * 16 + lr;
        a[mi] = *(const short8*)(la + row * 128 + ((ku ^ (row & 7)) << 4));
      }
#pragma unroll
      for (int nj = 0; nj < 8; nj++) {
        int row = wc * 128 + nj * 16 + lr;
        b[nj] = *(const short8*)(lb + row * 128 + ((ku ^ (row & 7)) << 4));
      }
#pragma unroll
      for (int mi = 0; mi < 4; mi++)
#pragma unroll
        for (int nj = 0; nj < 8; nj++)
          acc[mi][nj] = __builtin_amdgcn_mfma_f32_16x16x32_bf16(a[mi], b[nj], acc[mi][nj], 0, 0, 0);
    }
    __syncthreads();  // vmcnt(0)+lgkm drain + barrier: next buf ready, cur reusable
  }
#undef STAGE

  // Accumulate partial C. Bijection: w*8192 + frag*256 + e*64 + lane.
  float* Ct = Cbuf + (size_t)tile * 65536;
#pragma unroll
  for (int mi = 0; mi < 4; mi++)
#pragma unroll
    for (int nj = 0; nj < 8; nj++)
#pragma unroll
      for (int e = 0; e < 4; e++)
        atomicAdd(&Ct[w * 8192 + (mi * 8 + nj) * 256 + e * 64 + lane], acc[mi][nj][e]);
}

// 78*8 = 624 blocks: square+sum partial C with per-tile weights.
__global__ __launch_bounds__(256) void reduceC_k(const float* __restrict__ C, double* sums) {
  __shared__ double p[4];
  int bid = blockIdx.x, t = threadIdx.x;
  int tile = bid >> 3, seg = bid & 7;
  int m0, n0, which, diag;
  tile_decomp(tile, &m0, &n0, &which, &diag);
  double wgt = diag ? 1.0 : (which == 0 ? 1.0 : 2.0);

  const float* Ct = C + (size_t)tile * 65536 + (size_t)seg * 8192;
  double s = 0.0;
  for (int i = t * 4; i < 8192; i += 1024) {
    float4 v = *(const float4*)(Ct + i);
    s += (double)v.x * v.x + (double)v.y * v.y + (double)v.z * v.z + (double)v.w * v.w;
  }
  for (int off = 32; off; off >>= 1) s += __shfl_down(s, off, 64);
  if ((t & 63) == 0) p[t >> 6] = s;
  __syncthreads();
  if (t == 0) atomicAdd(&sums[which], wgt * (p[0] + p[1] + p[2] + p[3]));
}

// ---------------- Fallback path (R2, proven): no K-split, in-block reduce ----
__global__ __launch_bounds__(512, 2) void gemm_fro_k(const ushort* __restrict__ XT,
                                                     const ushort* __restrict__ YT,
                                                     double* sums) {
  __shared__ char lds[32768];
  __shared__ double part[8];
  char* ldsA = lds;
  char* ldsB = lds + 16384;

  int bid = blockIdx.x;
  const char* Ab; const char* Bb; int m0, n0, slot; double wgt;
  if (bid < 128) {
    int mt = bid >> 3, nt = bid & 7;
    Ab = (const char*)XT; Bb = (const char*)YT;
    m0 = mt * 128; n0 = nt * 128; wgt = 1.0; slot = 0;
  } else if (bid < 264) {
    int idx = bid - 128; int ti = 0;
    while (idx >= 16 - ti) { idx -= 16 - ti; ti++; }
    int tj = ti + idx;
    Ab = (const char*)XT; Bb = (const char*)XT;
    m0 = ti * 128; n0 = tj * 128; wgt = (ti == tj) ? 1.0 : 2.0; slot = 1;
  } else {
    int idx = bid - 264; int ti = 0;
    while (idx >= 8 - ti) { idx -= 8 - ti; ti++; }
    int tj = ti + idx;
    Ab = (const char*)YT; Bb = (const char*)YT;
    m0 = ti * 128; n0 = tj * 128; wgt = (ti == tj) ? 1.0 : 2.0; slot = 2;
  }

  int t = threadIdx.x;
  int row8 = t >> 3;
  int u = t & 7;
  int w = t >> 6;
  int lane = t & 63;
  int wm = (w >> 2) * 64, wn = (w & 3) * 32;
  int lr = lane & 15, lk = lane >> 4;

  f32x4 acc[4][2];
#pragma unroll
  for (int i = 0; i < 4; i++)
#pragma unroll
    for (int j = 0; j < 2; j++)
      acc[i][j] = (f32x4){0.f, 0.f, 0.f, 0.f};

  const size_t abase = (size_t)m0 * ROWB + (size_t)(u * 16);
  const size_t bbase = (size_t)n0 * ROWB + (size_t)(u * 16);

  for (int s = 0; s < K_DIM / 64; s++) {
    __syncthreads();
    size_t koff = (size_t)s * 128;
#pragma unroll
    for (int c = 0; c < 2; c++) {
      int row = c * 64 + row8;
      async16(Ab + abase + (size_t)row * ROWB + koff, ldsA + row * 128 + u * 16);
      async16(Bb + bbase + (size_t)row * ROWB + koff, ldsB + row * 128 + u * 16);
    }
    __syncthreads();

#pragma unroll
    for (int ks = 0; ks < 2; ks++) {
      short8 a[4], b[2];
#pragma unroll
      for (int mi = 0; mi < 4; mi++) {
        int row = wm + mi * 16 + lr;
        int ku = ks * 4 + lk;
        a[mi] = *(const short8*)(ldsA + row * 128 + ((ku ^ (row & 7)) << 4));
      }
#pragma unroll
      for (int nj = 0; nj < 2; nj++) {
        int row = wn + nj * 16 + lr;
        int ku = ks * 4 + lk;
        b[nj] = *(const short8*)(ldsB + row * 128 + ((ku ^ (row & 7)) << 4));
      }
#pragma unroll
      for (int mi = 0; mi < 4; mi++)
#pragma unroll
        for (int nj = 0; nj < 2; nj++)
          acc[mi][nj] = __builtin_amdgcn_mfma_f32_16x16x32_bf16(a[mi], b[nj], acc[mi][nj], 0, 0, 0);
    }
  }

  double local = 0.0;
#pragma unroll
  for (int mi = 0; mi < 4; mi++)
#pragma unroll
    for (int nj = 0; nj < 2; nj++)
#pragma unroll
      for (int e = 0; e < 4; e++) {
        double v = (double)acc[mi][nj][e];
        local += v * v;
      }

  for (int off = 32; off; off >>= 1) local += __shfl_down(local, off, 64);
  if (lane == 0) part[w] = local;
  __syncthreads();
  if (t == 0) {
    double tot = 0.0;
#pragma unroll
    for (int i = 0; i < 8; i++) tot += part[i];
    atomicAdd(&sums[slot], wgt * tot);
  }
}

__global__ void finalize_k(const double* sums, float* out) {
  double xy = sums[0], xx = sums[1], yy = sums[2];
  out[0] = (float)(xy / (sqrt(xx * yy) + 1e-8));
}

extern "C" void kernel_launch(void* const* d_in, const int* in_sizes, int n_in,
                              void* d_out, int out_size, void* d_ws, size_t ws_size,
                              hipStream_t stream) {
  (void)in_sizes; (void)n_in; (void)out_size;
  const float* x = (const float*)d_in[0];
  const float* y = (const float*)d_in[1];
  float* out = (float*)d_out;
  char* ws = (char*)d_ws;
  double* sums = (double*)ws;
  float* csx = (float*)(ws + 256);
  float* csy = (float*)(ws + 8448);
  ushort* XT = (ushort*)(ws + 16384);
  ushort* YT = (ushort*)(ws + 33570816);
  float* Cbuf = (float*)(ws + 50348032);
  const size_t NEED = 70795264;

  zero_k<<<1, 256, 0, stream>>>(sums, csx, csy);
  colsum_k<<<192, 256, 0, stream>>>(x, y, csx, csy);
  centerT_k<<<6144, 256, 0, stream>>>(x, y, csx, csy, XT, YT);
  if (ws_size >= NEED) {
    zeroC_k<<<1248, 256, 0, stream>>>(Cbuf);
    gemm_split_k<<<N_TILE * S_SPLIT, 512, 0, stream>>>(XT, YT, Cbuf);
    reduceC_k<<<N_TILE * 8, 256, 0, stream>>>(Cbuf, sums);
  } else {
    gemm_fro_k<<<300, 512, 0, stream>>>(XT, YT, sums);
  }
  finalize_k<<<1, 1, 0, stream>>>(sums, out);
}